// Round 1
// baseline (477.778 us; speedup 1.0000x reference)
//
#include <hip/hip_runtime.h>

constexpr int NN    = 100000;   // nodes
constexpr int NNZ_E = 1600000;  // sparse entries
constexpr int EQn   = 200000;   // edges to score
constexpr int INF_  = 256;
constexpr int HIDF  = 128;
constexpr int OUTF  = 64;

// ---------------------------------------------------------------------------
// CSR row_ptr from sorted rows: ptr[i] = lower_bound(rows, i)
// ---------------------------------------------------------------------------
__global__ __launch_bounds__(256) void build_row_ptr(const int* __restrict__ rows,
                                                     int* __restrict__ ptr) {
    int i = blockIdx.x * 256 + threadIdx.x;
    if (i > NN) return;
    int lo = 0, hi = NNZ_E;
    while (lo < hi) {
        int mid = (lo + hi) >> 1;
        if (rows[mid] < i) lo = mid + 1; else hi = mid;
    }
    ptr[i] = lo;
}

// ---------------------------------------------------------------------------
// Tiled fp32 GEMM + bias: C[M,NCOLS] = A[M,K] @ W[K,NCOLS] + bias
// 64x64 block tile, 256 threads, 4x4 micro-tile. K, NCOLS multiples of 32/64.
// ---------------------------------------------------------------------------
template<int K, int NCOLS>
__global__ __launch_bounds__(256) void gemm_bias(const float* __restrict__ A,
                                                 const float* __restrict__ W,
                                                 const float* __restrict__ bias,
                                                 float* __restrict__ C,
                                                 int M) {
    __shared__ float xs[64][33];   // +1 pad: breaks stride-32 bank aliasing
    __shared__ float wsh[32][64];

    const int tid  = threadIdx.x;
    const int row0 = blockIdx.x * 64;
    const int col0 = blockIdx.y * 64;
    const int tx = tid & 15;   // 16 col-groups * 4 cols
    const int ty = tid >> 4;   // 16 row-groups * 4 rows

    // staging maps
    const int lr  = tid >> 2;        // 0..63 row
    const int lk  = (tid & 3) * 8;   // 0,8,16,24
    const int lk2 = tid >> 3;        // 0..31 k
    const int lc  = (tid & 7) * 8;   // 0..56

    float acc[4][4] = {};

    for (int k0 = 0; k0 < K; k0 += 32) {
        int rsrc = row0 + lr; if (rsrc > M - 1) rsrc = M - 1;  // clamp (values unused)
        const float* xp = &A[(size_t)rsrc * K + k0 + lk];
        float4 v0 = *(const float4*)xp;
        float4 v1 = *(const float4*)(xp + 4);
        const float* wp = &W[(size_t)(k0 + lk2) * NCOLS + col0 + lc];
        float4 w0 = *(const float4*)wp;
        float4 w1 = *(const float4*)(wp + 4);

        __syncthreads();   // previous tile fully consumed
        xs[lr][lk+0]=v0.x; xs[lr][lk+1]=v0.y; xs[lr][lk+2]=v0.z; xs[lr][lk+3]=v0.w;
        xs[lr][lk+4]=v1.x; xs[lr][lk+5]=v1.y; xs[lr][lk+6]=v1.z; xs[lr][lk+7]=v1.w;
        *(float4*)&wsh[lk2][lc]     = w0;
        *(float4*)&wsh[lk2][lc + 4] = w1;
        __syncthreads();

        #pragma unroll
        for (int kk = 0; kk < 32; ++kk) {
            float a[4], b[4];
            #pragma unroll
            for (int i = 0; i < 4; ++i) a[i] = xs[ty * 4 + i][kk];
            #pragma unroll
            for (int j = 0; j < 4; ++j) b[j] = wsh[kk][tx * 4 + j];
            #pragma unroll
            for (int i = 0; i < 4; ++i)
                #pragma unroll
                for (int j = 0; j < 4; ++j)
                    acc[i][j] += a[i] * b[j];
        }
    }

    float4 bv = *(const float4*)&bias[col0 + tx * 4];
    #pragma unroll
    for (int i = 0; i < 4; ++i) {
        int r = row0 + ty * 4 + i;
        if (r < M) {
            float4 o;
            o.x = acc[i][0] + bv.x;
            o.y = acc[i][1] + bv.y;
            o.z = acc[i][2] + bv.z;
            o.w = acc[i][3] + bv.w;
            *(float4*)&C[(size_t)r * NCOLS + col0 + tx * 4] = o;
        }
    }
}

// ---------------------------------------------------------------------------
// Row-parallel CSR SpMM: out[i,:] = sum_e vals[e] * dense[cols[e],:]
// D/4 lanes per row, float4 gathers; optional fused ReLU.
// ---------------------------------------------------------------------------
template<int D, bool RELU>
__global__ __launch_bounds__(256) void spmm_csr(const int* __restrict__ ptr,
                                                const int* __restrict__ cols,
                                                const float* __restrict__ vals,
                                                const float* __restrict__ dense,
                                                float* __restrict__ outm) {
    constexpr int LPR = D / 4;       // lanes per row
    constexpr int RPB = 256 / LPR;   // rows per block
    const int lane = threadIdx.x % LPR;
    const int rr   = threadIdx.x / LPR;
    const int row  = blockIdx.x * RPB + rr;
    if (row >= NN) return;

    const int e1 = ptr[row + 1];
    float4 acc = make_float4(0.f, 0.f, 0.f, 0.f);
    for (int e = ptr[row]; e < e1; ++e) {
        const int   c = cols[e];
        const float v = vals[e];
        const float4 d4 = *(const float4*)&dense[(size_t)c * D + lane * 4];
        acc.x += v * d4.x; acc.y += v * d4.y;
        acc.z += v * d4.z; acc.w += v * d4.w;
    }
    if (RELU) {
        acc.x = fmaxf(acc.x, 0.f); acc.y = fmaxf(acc.y, 0.f);
        acc.z = fmaxf(acc.z, 0.f); acc.w = fmaxf(acc.w, 0.f);
    }
    *(float4*)&outm[(size_t)row * D + lane * 4] = acc;
}

// ---------------------------------------------------------------------------
// Decode: out[e] = dot(z[src[e]], z[dst[e]]), d=64. 16 lanes/edge.
// ---------------------------------------------------------------------------
__global__ __launch_bounds__(256) void decode_dot(const float* __restrict__ z,
                                                  const int* __restrict__ ei,
                                                  float* __restrict__ outv) {
    const int lane = threadIdx.x & 15;
    const int e    = blockIdx.x * 16 + (threadIdx.x >> 4);
    if (e >= EQn) return;
    const int s = ei[e];
    const int d = ei[EQn + e];
    float4 a = *(const float4*)&z[(size_t)s * 64 + lane * 4];
    float4 b = *(const float4*)&z[(size_t)d * 64 + lane * 4];
    float p = a.x * b.x + a.y * b.y + a.z * b.z + a.w * b.w;
    p += __shfl_xor(p, 1, 16);
    p += __shfl_xor(p, 2, 16);
    p += __shfl_xor(p, 4, 16);
    p += __shfl_xor(p, 8, 16);
    if (lane == 0) outv[e] = p;
}

// ---------------------------------------------------------------------------
extern "C" void kernel_launch(void* const* d_in, const int* in_sizes, int n_in,
                              void* d_out, int out_size, void* d_ws, size_t ws_size,
                              hipStream_t stream) {
    (void)in_sizes; (void)n_in; (void)out_size; (void)ws_size;

    const float* x        = (const float*)d_in[0];
    const int*   adj_rows = (const int*)  d_in[1];
    const int*   adj_cols = (const int*)  d_in[2];
    const float* adj_vals = (const float*)d_in[3];
    const int*   ei       = (const int*)  d_in[4];   // [2, EQ]
    const float* W1       = (const float*)d_in[5];
    const float* b1       = (const float*)d_in[6];
    const float* W2       = (const float*)d_in[7];
    const float* b2       = (const float*)d_in[8];
    float* out = (float*)d_out;

    // workspace layout: row_ptr | bufA [N,128] | bufB [N,128]
    char* ws = (char*)d_ws;
    int* row_ptr = (int*)ws;
    size_t off = ((size_t)(NN + 1) * sizeof(int) + 511) & ~(size_t)511;
    float* bufA = (float*)(ws + off);
    float* bufB = bufA + (size_t)NN * HIDF;

    build_row_ptr<<<(NN + 256) / 256, 256, 0, stream>>>(adj_rows, row_ptr);

    // h0 = x @ W1 + b1  -> bufA [N,128]
    gemm_bias<INF_, HIDF><<<dim3((NN + 63) / 64, HIDF / 64), 256, 0, stream>>>(
        x, W1, b1, bufA, NN);

    // h = relu(spmm(h0)) -> bufB [N,128]
    spmm_csr<HIDF, true><<<NN / (256 / (HIDF / 4)), 256, 0, stream>>>(
        row_ptr, adj_cols, adj_vals, bufA, bufB);

    // z0 = h @ W2 + b2 -> bufA [N,64]
    gemm_bias<HIDF, OUTF><<<dim3((NN + 63) / 64, OUTF / 64), 256, 0, stream>>>(
        bufB, W2, b2, bufA, NN);

    // z = spmm(z0) -> bufB [N,64]
    spmm_csr<OUTF, false><<<NN / (256 / (OUTF / 4)), 256, 0, stream>>>(
        row_ptr, adj_cols, adj_vals, bufA, bufB);

    // out[e] = dot(z[src], z[dst])
    decode_dot<<<EQn / 16, 256, 0, stream>>>(bufB, ei, out);
}

// Round 2
// 405.488 us; speedup vs baseline: 1.1783x; 1.1783x over previous
//
#include <hip/hip_runtime.h>

constexpr int NN    = 100000;   // nodes
constexpr int NNZ_E = 1600000;  // sparse entries
constexpr int EQn   = 200000;   // edges to score
constexpr int INF_  = 256;
constexpr int HIDF  = 128;
constexpr int OUTF  = 64;

// fp32 -> bf16 (round to nearest even)
__device__ inline unsigned short f2bf(float f) {
    union { float f; unsigned int i; } x; x.f = f;
    unsigned int r = x.i + 0x7fffu + ((x.i >> 16) & 1u);
    return (unsigned short)(r >> 16);
}

// ---------------------------------------------------------------------------
// CSR row_ptr from sorted rows: ptr[i] = lower_bound(rows, i)
// ---------------------------------------------------------------------------
__global__ __launch_bounds__(256) void build_row_ptr(const int* __restrict__ rows,
                                                     int* __restrict__ ptr) {
    int i = blockIdx.x * 256 + threadIdx.x;
    if (i > NN) return;
    int lo = 0, hi = NNZ_E;
    while (lo < hi) {
        int mid = (lo + hi) >> 1;
        if (rows[mid] < i) lo = mid + 1; else hi = mid;
    }
    ptr[i] = lo;
}

// ---------------------------------------------------------------------------
// Tiled fp32 GEMM + bias, output stored as bf16 (row-major, stride NCOLS).
// 64x64 block tile, 256 threads, 4x4 micro-tile.
// ---------------------------------------------------------------------------
template<int K, int NCOLS>
__global__ __launch_bounds__(256) void gemm_bias_bf16out(const float* __restrict__ A,
                                                         const float* __restrict__ W,
                                                         const float* __restrict__ bias,
                                                         unsigned short* __restrict__ C,
                                                         int M) {
    __shared__ float xs[64][33];   // +1 pad breaks stride-32 bank aliasing
    __shared__ float wsh[32][64];

    const int tid  = threadIdx.x;
    const int row0 = blockIdx.x * 64;
    const int col0 = blockIdx.y * 64;
    const int tx = tid & 15;   // 16 col-groups * 4 cols
    const int ty = tid >> 4;   // 16 row-groups * 4 rows

    const int lr  = tid >> 2;        // 0..63 row
    const int lk  = (tid & 3) * 8;   // 0,8,16,24
    const int lk2 = tid >> 3;        // 0..31 k
    const int lc  = (tid & 7) * 8;   // 0..56

    float acc[4][4] = {};

    for (int k0 = 0; k0 < K; k0 += 32) {
        int rsrc = row0 + lr; if (rsrc > M - 1) rsrc = M - 1;  // clamp
        const float* xp = &A[(size_t)rsrc * K + k0 + lk];
        float4 v0 = *(const float4*)xp;
        float4 v1 = *(const float4*)(xp + 4);
        const float* wp = &W[(size_t)(k0 + lk2) * NCOLS + col0 + lc];
        float4 w0 = *(const float4*)wp;
        float4 w1 = *(const float4*)(wp + 4);

        __syncthreads();
        xs[lr][lk+0]=v0.x; xs[lr][lk+1]=v0.y; xs[lr][lk+2]=v0.z; xs[lr][lk+3]=v0.w;
        xs[lr][lk+4]=v1.x; xs[lr][lk+5]=v1.y; xs[lr][lk+6]=v1.z; xs[lr][lk+7]=v1.w;
        *(float4*)&wsh[lk2][lc]     = w0;
        *(float4*)&wsh[lk2][lc + 4] = w1;
        __syncthreads();

        #pragma unroll
        for (int kk = 0; kk < 32; ++kk) {
            float a[4], b[4];
            #pragma unroll
            for (int i = 0; i < 4; ++i) a[i] = xs[ty * 4 + i][kk];
            #pragma unroll
            for (int j = 0; j < 4; ++j) b[j] = wsh[kk][tx * 4 + j];
            #pragma unroll
            for (int i = 0; i < 4; ++i)
                #pragma unroll
                for (int j = 0; j < 4; ++j)
                    acc[i][j] += a[i] * b[j];
        }
    }

    float4 bv = *(const float4*)&bias[col0 + tx * 4];
    #pragma unroll
    for (int i = 0; i < 4; ++i) {
        int r = row0 + ty * 4 + i;
        if (r < M) {
            ushort4 o;
            o.x = f2bf(acc[i][0] + bv.x);
            o.y = f2bf(acc[i][1] + bv.y);
            o.z = f2bf(acc[i][2] + bv.z);
            o.w = f2bf(acc[i][3] + bv.w);
            *(ushort4*)&C[(size_t)r * NCOLS + col0 + tx * 4] = o;  // 8 B store
        }
    }
}

// ---------------------------------------------------------------------------
// Row-parallel CSR SpMM over a bf16 table: out[i,:] = sum_e vals[e]*dense[cols[e],:]
// D/8 lanes per row, 16 B (8 bf16) per lane per edge; fp32 accumulate.
// ---------------------------------------------------------------------------
template<int D, bool RELU>
__global__ __launch_bounds__(256) void spmm_bf16(const int* __restrict__ ptr,
                                                 const int* __restrict__ cols,
                                                 const float* __restrict__ vals,
                                                 const unsigned short* __restrict__ dense,
                                                 float* __restrict__ outm) {
    constexpr int LPR = D / 8;       // lanes per row
    constexpr int RPB = 256 / LPR;   // rows per block
    const int lane = threadIdx.x % LPR;
    const int row  = blockIdx.x * RPB + threadIdx.x / LPR;
    if (row >= NN) return;

    const int e1 = ptr[row + 1];
    float acc[8] = {};
    for (int e = ptr[row]; e < e1; ++e) {
        const int   c = cols[e];
        const float v = vals[e];
        uint4 q = *(const uint4*)&dense[(size_t)c * D + lane * 8];  // 8 bf16
        union { unsigned int i; float f; } t;
        #pragma unroll
        for (int p = 0; p < 4; ++p) {
            unsigned int w = (&q.x)[p];
            t.i = w << 16;          acc[2*p]   += v * t.f;  // low bf16
            t.i = w & 0xffff0000u;  acc[2*p+1] += v * t.f;  // high bf16
        }
    }
    if (RELU) {
        #pragma unroll
        for (int p = 0; p < 8; ++p) acc[p] = fmaxf(acc[p], 0.f);
    }
    float* op = &outm[(size_t)row * D + lane * 8];
    *(float4*)op       = make_float4(acc[0], acc[1], acc[2], acc[3]);
    *(float4*)(op + 4) = make_float4(acc[4], acc[5], acc[6], acc[7]);
}

// ---------------------------------------------------------------------------
// Decode: out[e] = dot(z[src[e]], z[dst[e]]), d=64. 16 lanes/edge.
// ---------------------------------------------------------------------------
__global__ __launch_bounds__(256) void decode_dot(const float* __restrict__ z,
                                                  const int* __restrict__ ei,
                                                  float* __restrict__ outv) {
    const int lane = threadIdx.x & 15;
    const int e    = blockIdx.x * 16 + (threadIdx.x >> 4);
    if (e >= EQn) return;
    const int s = ei[e];
    const int d = ei[EQn + e];
    float4 a = *(const float4*)&z[(size_t)s * 64 + lane * 4];
    float4 b = *(const float4*)&z[(size_t)d * 64 + lane * 4];
    float p = a.x * b.x + a.y * b.y + a.z * b.z + a.w * b.w;
    p += __shfl_xor(p, 1, 16);
    p += __shfl_xor(p, 2, 16);
    p += __shfl_xor(p, 4, 16);
    p += __shfl_xor(p, 8, 16);
    if (lane == 0) outv[e] = p;
}

// ---------------------------------------------------------------------------
extern "C" void kernel_launch(void* const* d_in, const int* in_sizes, int n_in,
                              void* d_out, int out_size, void* d_ws, size_t ws_size,
                              hipStream_t stream) {
    (void)in_sizes; (void)n_in; (void)out_size; (void)ws_size;

    const float* x        = (const float*)d_in[0];
    const int*   adj_rows = (const int*)  d_in[1];
    const int*   adj_cols = (const int*)  d_in[2];
    const float* adj_vals = (const float*)d_in[3];
    const int*   ei       = (const int*)  d_in[4];   // [2, EQ]
    const float* W1       = (const float*)d_in[5];
    const float* b1       = (const float*)d_in[6];
    const float* W2       = (const float*)d_in[7];
    const float* b2       = (const float*)d_in[8];
    float* out = (float*)d_out;

    // workspace: row_ptr | slotA (bf16 tables: h0 then z0) | slotB (fp32: h then z)
    char* ws = (char*)d_ws;
    int* row_ptr = (int*)ws;
    size_t off = ((size_t)(NN + 1) * sizeof(int) + 511) & ~(size_t)511;
    unsigned short* slotA = (unsigned short*)(ws + off);          // 25.6 MB max
    float* slotB = (float*)((char*)slotA + (size_t)NN * HIDF * sizeof(unsigned short));

    build_row_ptr<<<(NN + 256) / 256, 256, 0, stream>>>(adj_rows, row_ptr);

    // h0 = x @ W1 + b1  -> slotA bf16 [N,128]
    gemm_bias_bf16out<INF_, HIDF><<<dim3((NN + 63) / 64, HIDF / 64), 256, 0, stream>>>(
        x, W1, b1, slotA, NN);

    // h = relu(spmm(h0)) -> slotB fp32 [N,128]
    spmm_bf16<HIDF, true><<<(NN + 15) / 16, 256, 0, stream>>>(
        row_ptr, adj_cols, adj_vals, slotA, slotB);

    // z0 = h @ W2 + b2 -> slotA bf16 [N,64]   (h0 dead, reuse slot)
    gemm_bias_bf16out<HIDF, OUTF><<<dim3((NN + 63) / 64, OUTF / 64), 256, 0, stream>>>(
        slotB, W2, b2, slotA, NN);

    // z = spmm(z0) -> slotB fp32 [N,64]       (h dead after GEMM2)
    spmm_bf16<OUTF, false><<<(NN + 31) / 32, 256, 0, stream>>>(
        row_ptr, adj_cols, adj_vals, slotA, slotB);

    // out[e] = dot(z[src], z[dst])
    decode_dot<<<EQn / 16, 256, 0, stream>>>(slotB, ei, out);
}

// Round 3
// 383.781 us; speedup vs baseline: 1.2449x; 1.0566x over previous
//
#include <hip/hip_runtime.h>

constexpr int NN    = 100000;   // nodes
constexpr int NNZ_E = 1600000;  // sparse entries
constexpr int EQn   = 200000;   // edges to score
constexpr int INF_  = 256;
constexpr int HIDF  = 128;
constexpr int OUTF  = 64;

typedef float  f32x4  __attribute__((ext_vector_type(4)));
typedef short  bf16x8 __attribute__((ext_vector_type(8)));

// fp32 -> bf16 (round to nearest even)
__device__ inline unsigned short f2bf(float f) {
    union { float f; unsigned int i; } x; x.f = f;
    unsigned int r = x.i + 0x7fffu + ((x.i >> 16) & 1u);
    return (unsigned short)(r >> 16);
}

// ---------------------------------------------------------------------------
// CSR row_ptr from sorted rows: ptr[i] = lower_bound(rows, i)
// ---------------------------------------------------------------------------
__global__ __launch_bounds__(256) void build_row_ptr(const int* __restrict__ rows,
                                                     int* __restrict__ ptr) {
    int i = blockIdx.x * 256 + threadIdx.x;
    if (i > NN) return;
    int lo = 0, hi = NNZ_E;
    while (lo < hi) {
        int mid = (lo + hi) >> 1;
        if (rows[mid] < i) lo = mid + 1; else hi = mid;
    }
    ptr[i] = lo;
}

// ---------------------------------------------------------------------------
// One-shot: W[k][n] fp32 -> Wt[n][k] bf16 for both layers (tiny).
// ---------------------------------------------------------------------------
__global__ __launch_bounds__(256) void convert_weights(const float* __restrict__ W1,
                                                       const float* __restrict__ W2,
                                                       unsigned short* __restrict__ W1t,
                                                       unsigned short* __restrict__ W2t) {
    int i = blockIdx.x * 256 + threadIdx.x;
    if (i < INF_ * HIDF) {            // W1 [256][128]
        int k = i >> 7, n = i & 127;
        W1t[n * INF_ + k] = f2bf(W1[i]);
    }
    if (i < HIDF * OUTF) {            // W2 [128][64]
        int k = i >> 6, n = i & 63;
        W2t[n * HIDF + k] = f2bf(W2[i]);
    }
}

// ---------------------------------------------------------------------------
// MFMA bf16 GEMM: C_bf16[M,NCOLS] = A_f32[M,K] @ W (Wt bf16 [NCOLS][K]) + bias.
// Block: 64 rows x NCOLS cols, 256 threads = 4 waves, each wave a 16-row band.
// K staged in 64-chunks; A converted fp32->bf16 in-register during staging.
// LDS rows padded to 72 bf16 (144 B) -> <=2-way conflicts on ds_read_b128.
// ---------------------------------------------------------------------------
template<int K, int NCOLS>
__global__ __launch_bounds__(256) void gemm_mfma(const float* __restrict__ A,
                                                 const unsigned short* __restrict__ Bt,
                                                 const float* __restrict__ bias,
                                                 unsigned short* __restrict__ C,
                                                 int M) {
    constexpr int PAD = 72;
    constexpr int NT  = NCOLS / 16;            // 16x16 tiles per wave
    __shared__ unsigned short As[64 * PAD];
    __shared__ unsigned short Bs[NCOLS * PAD];

    const int tid  = threadIdx.x;
    const int wave = tid >> 6;
    const int lane = tid & 63;
    const int quad = lane >> 4;
    const int l16  = lane & 15;
    const int row0 = blockIdx.x * 64;

    f32x4 acc[NT];
    #pragma unroll
    for (int t = 0; t < NT; ++t) acc[t] = (f32x4){0.f, 0.f, 0.f, 0.f};

    // staging maps
    const int ar  = tid >> 2;            // A row 0..63
    const int ak  = (tid & 3) * 16;      // A k-offset 0/16/32/48
    constexpr int CPT = NCOLS / 32;      // B 16B-chunks per thread (4 or 2)

    for (int k0 = 0; k0 < K; k0 += 64) {
        // global loads first (overlap with previous tile's compute)
        int rsrc = row0 + ar; if (rsrc > M - 1) rsrc = M - 1;
        const float* ap = &A[(size_t)rsrc * K + k0 + ak];
        float4 av[4];
        #pragma unroll
        for (int i = 0; i < 4; ++i) av[i] = *(const float4*)(ap + i * 4);

        uint4 bv[CPT];
        #pragma unroll
        for (int i = 0; i < CPT; ++i) {
            int c = tid * CPT + i;
            int n = c >> 3, kc = (c & 7) * 8;
            bv[i] = *(const uint4*)&Bt[(size_t)n * K + k0 + kc];
        }

        __syncthreads();   // previous tile fully consumed
        #pragma unroll
        for (int i = 0; i < 4; ++i) {
            ushort4 u;
            u.x = f2bf(av[i].x); u.y = f2bf(av[i].y);
            u.z = f2bf(av[i].z); u.w = f2bf(av[i].w);
            *(ushort4*)&As[ar * PAD + ak + i * 4] = u;
        }
        #pragma unroll
        for (int i = 0; i < CPT; ++i) {
            int c = tid * CPT + i;
            int n = c >> 3, kc = (c & 7) * 8;
            *(uint4*)&Bs[n * PAD + kc] = bv[i];
        }
        __syncthreads();

        #pragma unroll
        for (int ks = 0; ks < 2; ++ks) {
            const int koff = ks * 32 + quad * 8;
            bf16x8 af = *(const bf16x8*)&As[(wave * 16 + l16) * PAD + koff];
            #pragma unroll
            for (int t = 0; t < NT; ++t) {
                bf16x8 bf = *(const bf16x8*)&Bs[(t * 16 + l16) * PAD + koff];
                acc[t] = __builtin_amdgcn_mfma_f32_16x16x32_bf16(af, bf, acc[t], 0, 0, 0);
            }
        }
    }

    // epilogue: C/D layout col=lane&15, row=quad*4+reg
    #pragma unroll
    for (int t = 0; t < NT; ++t) {
        const int col = t * 16 + l16;
        const float bb = bias[col];
        #pragma unroll
        for (int r = 0; r < 4; ++r) {
            int row = row0 + wave * 16 + quad * 4 + r;
            if (row < M) C[(size_t)row * NCOLS + col] = f2bf(acc[t][r] + bb);
        }
    }
}

// ---------------------------------------------------------------------------
// Row-parallel CSR SpMM over a bf16 table: out[i,:] = sum_e vals[e]*dense[cols[e],:]
// D/8 lanes per row, 16 B (8 bf16) per lane per edge; fp32 accumulate.
// ---------------------------------------------------------------------------
template<int D, bool RELU>
__global__ __launch_bounds__(256) void spmm_bf16(const int* __restrict__ ptr,
                                                 const int* __restrict__ cols,
                                                 const float* __restrict__ vals,
                                                 const unsigned short* __restrict__ dense,
                                                 float* __restrict__ outm) {
    constexpr int LPR = D / 8;       // lanes per row
    constexpr int RPB = 256 / LPR;   // rows per block
    const int lane = threadIdx.x % LPR;
    const int row  = blockIdx.x * RPB + threadIdx.x / LPR;
    if (row >= NN) return;

    const int e1 = ptr[row + 1];
    float acc[8] = {};
    for (int e = ptr[row]; e < e1; ++e) {
        const int   c = cols[e];
        const float v = vals[e];
        uint4 q = *(const uint4*)&dense[(size_t)c * D + lane * 8];  // 8 bf16
        union { unsigned int i; float f; } t;
        #pragma unroll
        for (int p = 0; p < 4; ++p) {
            unsigned int w = (&q.x)[p];
            t.i = w << 16;          acc[2*p]   += v * t.f;  // low bf16
            t.i = w & 0xffff0000u;  acc[2*p+1] += v * t.f;  // high bf16
        }
    }
    if (RELU) {
        #pragma unroll
        for (int p = 0; p < 8; ++p) acc[p] = fmaxf(acc[p], 0.f);
    }
    float* op = &outm[(size_t)row * D + lane * 8];
    *(float4*)op       = make_float4(acc[0], acc[1], acc[2], acc[3]);
    *(float4*)(op + 4) = make_float4(acc[4], acc[5], acc[6], acc[7]);
}

// ---------------------------------------------------------------------------
// Decode: out[e] = dot(z[src[e]], z[dst[e]]), d=64. 16 lanes/edge.
// ---------------------------------------------------------------------------
__global__ __launch_bounds__(256) void decode_dot(const float* __restrict__ z,
                                                  const int* __restrict__ ei,
                                                  float* __restrict__ outv) {
    const int lane = threadIdx.x & 15;
    const int e    = blockIdx.x * 16 + (threadIdx.x >> 4);
    if (e >= EQn) return;
    const int s = ei[e];
    const int d = ei[EQn + e];
    float4 a = *(const float4*)&z[(size_t)s * 64 + lane * 4];
    float4 b = *(const float4*)&z[(size_t)d * 64 + lane * 4];
    float p = a.x * b.x + a.y * b.y + a.z * b.z + a.w * b.w;
    p += __shfl_xor(p, 1, 16);
    p += __shfl_xor(p, 2, 16);
    p += __shfl_xor(p, 4, 16);
    p += __shfl_xor(p, 8, 16);
    if (lane == 0) outv[e] = p;
}

// ---------------------------------------------------------------------------
extern "C" void kernel_launch(void* const* d_in, const int* in_sizes, int n_in,
                              void* d_out, int out_size, void* d_ws, size_t ws_size,
                              hipStream_t stream) {
    (void)in_sizes; (void)n_in; (void)out_size; (void)ws_size;

    const float* x        = (const float*)d_in[0];
    const int*   adj_rows = (const int*)  d_in[1];
    const int*   adj_cols = (const int*)  d_in[2];
    const float* adj_vals = (const float*)d_in[3];
    const int*   ei       = (const int*)  d_in[4];   // [2, EQ]
    const float* W1       = (const float*)d_in[5];
    const float* b1       = (const float*)d_in[6];
    const float* W2       = (const float*)d_in[7];
    const float* b2       = (const float*)d_in[8];
    float* out = (float*)d_out;

    // workspace: row_ptr | W1t | W2t | slotA (bf16 h0/z0) | slotB (fp32 h/z)
    char* ws = (char*)d_ws;
    int* row_ptr = (int*)ws;
    size_t off = ((size_t)(NN + 1) * sizeof(int) + 511) & ~(size_t)511;
    unsigned short* W1t = (unsigned short*)(ws + off);              // 64 KB
    unsigned short* W2t = W1t + (size_t)HIDF * INF_;                // 16 KB
    unsigned short* slotA = W2t + (size_t)OUTF * HIDF;
    // align slotA to 512
    slotA = (unsigned short*)(((size_t)slotA + 511) & ~(size_t)511);
    float* slotB = (float*)((char*)slotA + (size_t)NN * HIDF * sizeof(unsigned short));

    build_row_ptr<<<(NN + 256) / 256, 256, 0, stream>>>(adj_rows, row_ptr);
    convert_weights<<<(INF_ * HIDF + 255) / 256, 256, 0, stream>>>(W1, W2, W1t, W2t);

    // h0 = x @ W1 + b1  -> slotA bf16 [N,128]
    gemm_mfma<INF_, HIDF><<<(NN + 63) / 64, 256, 0, stream>>>(x, W1t, b1, slotA, NN);

    // h = relu(spmm(h0)) -> slotB fp32 [N,128]
    spmm_bf16<HIDF, true><<<(NN + 15) / 16, 256, 0, stream>>>(
        row_ptr, adj_cols, adj_vals, slotA, slotB);

    // z0 = h @ W2 + b2 -> slotA bf16 [N,64]
    gemm_mfma<HIDF, OUTF><<<(NN + 63) / 64, 256, 0, stream>>>(slotB, W2t, b2, slotA, NN);

    // z = spmm(z0) -> slotB fp32 [N,64]
    spmm_bf16<OUTF, false><<<(NN + 31) / 32, 256, 0, stream>>>(
        row_ptr, adj_cols, adj_vals, slotA, slotB);

    // out[e] = dot(z[src], z[dst])
    decode_dot<<<EQn / 16, 256, 0, stream>>>(slotB, ei, out);
}

// Round 4
// 369.816 us; speedup vs baseline: 1.2919x; 1.0378x over previous
//
#include <hip/hip_runtime.h>

constexpr int NN    = 100000;   // nodes
constexpr int NNZ_E = 1600000;  // sparse entries
constexpr int EQn   = 200000;   // edges to score
constexpr int INF_  = 256;
constexpr int HIDF  = 128;
constexpr int OUTF  = 64;

typedef float  f32x4  __attribute__((ext_vector_type(4)));
typedef short  bf16x8 __attribute__((ext_vector_type(8)));

// fp32 -> bf16 (round to nearest even)
__device__ inline unsigned short f2bf(float f) {
    union { float f; unsigned int i; } x; x.f = f;
    unsigned int r = x.i + 0x7fffu + ((x.i >> 16) & 1u);
    return (unsigned short)(r >> 16);
}

// ---------------------------------------------------------------------------
// CSR row_ptr from sorted rows: ptr[i] = lower_bound(rows, i)
// ---------------------------------------------------------------------------
__global__ __launch_bounds__(256) void build_row_ptr(const int* __restrict__ rows,
                                                     int* __restrict__ ptr) {
    int i = blockIdx.x * 256 + threadIdx.x;
    if (i > NN) return;
    int lo = 0, hi = NNZ_E;
    while (lo < hi) {
        int mid = (lo + hi) >> 1;
        if (rows[mid] < i) lo = mid + 1; else hi = mid;
    }
    ptr[i] = lo;
}

// ---------------------------------------------------------------------------
// One-shot: W[k][n] fp32 -> Wt[n][k] bf16 for both layers (tiny).
// ---------------------------------------------------------------------------
__global__ __launch_bounds__(256) void convert_weights(const float* __restrict__ W1,
                                                       const float* __restrict__ W2,
                                                       unsigned short* __restrict__ W1t,
                                                       unsigned short* __restrict__ W2t) {
    int i = blockIdx.x * 256 + threadIdx.x;
    if (i < INF_ * HIDF) {            // W1 [256][128]
        int k = i >> 7, n = i & 127;
        W1t[n * INF_ + k] = f2bf(W1[i]);
    }
    if (i < HIDF * OUTF) {            // W2 [128][64]
        int k = i >> 6, n = i & 63;
        W2t[n * HIDF + k] = f2bf(W2[i]);
    }
}

// ---------------------------------------------------------------------------
// Barrier-free MFMA GEMM: C_bf16[M,NCOLS] = A_f32[M,K] @ Wt_bf16[NCOLS][K] + b.
// No LDS staging in the K-loop: A fragments loaded straight from global
// (2 float4/lane per k-step, converted to bf16 in-register); B fragments
// straight from Wt (all 4 quads of a row share one 64B line; Wt is L2-hot).
// Fully unrolled K -> ~10*KS independent loads in flight per wave.
// Epilogue staged through per-wave LDS for coalesced 16B global stores.
// ---------------------------------------------------------------------------
template<int K, int NCOLS>
__global__ __launch_bounds__(256) void gemm_mfma_direct(const float* __restrict__ A,
                                                        const unsigned short* __restrict__ Bt,
                                                        const float* __restrict__ bias,
                                                        unsigned short* __restrict__ C,
                                                        int M) {
    constexpr int NT   = NCOLS / 16;   // 16x16 tiles per wave (cols)
    constexpr int KS   = K / 32;       // k-steps
    constexpr int PADW = NCOLS + 8;    // ushort stride: 16B-aligned, bank-spread
    __shared__ unsigned short cst[4 * 16 * PADW];

    const int tid  = threadIdx.x;
    const int wave = tid >> 6;
    const int lane = tid & 63;
    const int quad = lane >> 4;
    const int l16  = lane & 15;
    const int row0w = blockIdx.x * 64 + wave * 16;

    int arow = row0w + l16; if (arow > M - 1) arow = M - 1;   // clamp (tail garbage unused)
    const float*          ap = &A[(size_t)arow * K + quad * 8];
    const unsigned short* bp = &Bt[(size_t)l16 * K + quad * 8];

    f32x4 acc[NT];
    #pragma unroll
    for (int t = 0; t < NT; ++t) acc[t] = (f32x4){0.f, 0.f, 0.f, 0.f};

    #pragma unroll
    for (int ks = 0; ks < KS; ++ks) {
        float4 a0 = *(const float4*)(ap + ks * 32);
        float4 a1 = *(const float4*)(ap + ks * 32 + 4);
        bf16x8 af;
        af[0] = (short)f2bf(a0.x); af[1] = (short)f2bf(a0.y);
        af[2] = (short)f2bf(a0.z); af[3] = (short)f2bf(a0.w);
        af[4] = (short)f2bf(a1.x); af[5] = (short)f2bf(a1.y);
        af[6] = (short)f2bf(a1.z); af[7] = (short)f2bf(a1.w);
        #pragma unroll
        for (int t = 0; t < NT; ++t) {
            bf16x8 bf = *(const bf16x8*)(bp + (size_t)t * 16 * K + ks * 32);
            acc[t] = __builtin_amdgcn_mfma_f32_16x16x32_bf16(af, bf, acc[t], 0, 0, 0);
        }
    }

    // ---- epilogue: C/D layout col=lane&15, row=quad*4+reg ----
    unsigned short* my = &cst[wave * 16 * PADW];
    #pragma unroll
    for (int t = 0; t < NT; ++t) {
        const float bb = bias[t * 16 + l16];
        #pragma unroll
        for (int r = 0; r < 4; ++r)
            my[(quad * 4 + r) * PADW + t * 16 + l16] = f2bf(acc[t][r] + bb);
    }
    __syncthreads();
    constexpr int CH = NCOLS / 8;          // 16B chunks per row
    #pragma unroll
    for (int i = 0; i < CH / 4; ++i) {
        int id = i * 64 + lane;
        int r  = id / CH, cc = id % CH;
        int grow = row0w + r;
        if (grow < M)
            *(uint4*)&C[(size_t)grow * NCOLS + cc * 8] =
                *(const uint4*)&my[r * PADW + cc * 8];
    }
}

// ---------------------------------------------------------------------------
// Row-parallel CSR SpMM over a bf16 table: out[i,:] = sum_e vals[e]*dense[cols[e],:]
// D/8 lanes per row, 16 B (8 bf16) per lane per edge; fp32 accumulate.
// ---------------------------------------------------------------------------
template<int D, bool RELU>
__global__ __launch_bounds__(256) void spmm_bf16(const int* __restrict__ ptr,
                                                 const int* __restrict__ cols,
                                                 const float* __restrict__ vals,
                                                 const unsigned short* __restrict__ dense,
                                                 float* __restrict__ outm) {
    constexpr int LPR = D / 8;       // lanes per row
    constexpr int RPB = 256 / LPR;   // rows per block
    const int lane = threadIdx.x % LPR;
    const int row  = blockIdx.x * RPB + threadIdx.x / LPR;
    if (row >= NN) return;

    const int e1 = ptr[row + 1];
    float acc[8] = {};
    for (int e = ptr[row]; e < e1; ++e) {
        const int   c = cols[e];
        const float v = vals[e];
        uint4 q = *(const uint4*)&dense[(size_t)c * D + lane * 8];  // 8 bf16
        union { unsigned int i; float f; } t;
        #pragma unroll
        for (int p = 0; p < 4; ++p) {
            unsigned int w = (&q.x)[p];
            t.i = w << 16;          acc[2*p]   += v * t.f;  // low bf16
            t.i = w & 0xffff0000u;  acc[2*p+1] += v * t.f;  // high bf16
        }
    }
    if (RELU) {
        #pragma unroll
        for (int p = 0; p < 8; ++p) acc[p] = fmaxf(acc[p], 0.f);
    }
    float* op = &outm[(size_t)row * D + lane * 8];
    *(float4*)op       = make_float4(acc[0], acc[1], acc[2], acc[3]);
    *(float4*)(op + 4) = make_float4(acc[4], acc[5], acc[6], acc[7]);
}

// ---------------------------------------------------------------------------
// Decode: out[e] = dot(z[src[e]], z[dst[e]]), d=64. 16 lanes/edge.
// ---------------------------------------------------------------------------
__global__ __launch_bounds__(256) void decode_dot(const float* __restrict__ z,
                                                  const int* __restrict__ ei,
                                                  float* __restrict__ outv) {
    const int lane = threadIdx.x & 15;
    const int e    = blockIdx.x * 16 + (threadIdx.x >> 4);
    if (e >= EQn) return;
    const int s = ei[e];
    const int d = ei[EQn + e];
    float4 a = *(const float4*)&z[(size_t)s * 64 + lane * 4];
    float4 b = *(const float4*)&z[(size_t)d * 64 + lane * 4];
    float p = a.x * b.x + a.y * b.y + a.z * b.z + a.w * b.w;
    p += __shfl_xor(p, 1, 16);
    p += __shfl_xor(p, 2, 16);
    p += __shfl_xor(p, 4, 16);
    p += __shfl_xor(p, 8, 16);
    if (lane == 0) outv[e] = p;
}

// ---------------------------------------------------------------------------
extern "C" void kernel_launch(void* const* d_in, const int* in_sizes, int n_in,
                              void* d_out, int out_size, void* d_ws, size_t ws_size,
                              hipStream_t stream) {
    (void)in_sizes; (void)n_in; (void)out_size; (void)ws_size;

    const float* x        = (const float*)d_in[0];
    const int*   adj_rows = (const int*)  d_in[1];
    const int*   adj_cols = (const int*)  d_in[2];
    const float* adj_vals = (const float*)d_in[3];
    const int*   ei       = (const int*)  d_in[4];   // [2, EQ]
    const float* W1       = (const float*)d_in[5];
    const float* b1       = (const float*)d_in[6];
    const float* W2       = (const float*)d_in[7];
    const float* b2       = (const float*)d_in[8];
    float* out = (float*)d_out;

    // workspace: row_ptr | W1t | W2t | slotA (bf16 h0/z0) | slotB (fp32 h/z)
    char* ws = (char*)d_ws;
    int* row_ptr = (int*)ws;
    size_t off = ((size_t)(NN + 1) * sizeof(int) + 511) & ~(size_t)511;
    unsigned short* W1t = (unsigned short*)(ws + off);              // 64 KB
    unsigned short* W2t = W1t + (size_t)HIDF * INF_;                // 16 KB
    unsigned short* slotA = W2t + (size_t)OUTF * HIDF;
    slotA = (unsigned short*)(((size_t)slotA + 511) & ~(size_t)511);
    float* slotB = (float*)((char*)slotA + (size_t)NN * HIDF * sizeof(unsigned short));

    build_row_ptr<<<(NN + 256) / 256, 256, 0, stream>>>(adj_rows, row_ptr);
    convert_weights<<<(INF_ * HIDF + 255) / 256, 256, 0, stream>>>(W1, W2, W1t, W2t);

    // h0 = x @ W1 + b1  -> slotA bf16 [N,128]
    gemm_mfma_direct<INF_, HIDF><<<(NN + 63) / 64, 256, 0, stream>>>(x, W1t, b1, slotA, NN);

    // h = relu(spmm(h0)) -> slotB fp32 [N,128]
    spmm_bf16<HIDF, true><<<(NN + 15) / 16, 256, 0, stream>>>(
        row_ptr, adj_cols, adj_vals, slotA, slotB);

    // z0 = h @ W2 + b2 -> slotA bf16 [N,64]
    gemm_mfma_direct<HIDF, OUTF><<<(NN + 63) / 64, 256, 0, stream>>>(slotB, W2t, b2, slotA, NN);

    // z = spmm(z0) -> slotB fp32 [N,64]
    spmm_bf16<OUTF, false><<<(NN + 31) / 32, 256, 0, stream>>>(
        row_ptr, adj_cols, adj_vals, slotA, slotB);

    // out[e] = dot(z[src], z[dst])
    decode_dot<<<EQn / 16, 256, 0, stream>>>(slotB, ei, out);
}